// Round 14
// baseline (320.820 us; speedup 1.0000x reference)
//
#include <hip/hip_runtime.h>
#include <hip/hip_bf16.h>
#include <math.h>

typedef __bf16 bf16x8 __attribute__((ext_vector_type(8)));
typedef float  f32x4  __attribute__((ext_vector_type(4)));
typedef unsigned int u32;

#define BS 4
#define CH 256
#define HW 4096
#define QB 64           // q-rows per block
#define KB 64           // j per k-tile
#define NKT (HW/KB)     // 64
#define NQT (HW/QB)     // 64
#define LOG2E 1.44269504f

// PV k-slot permutation: j local (0..63) -> u, so a lane's S^T outputs are its PV B slots.
// j = jh*32 + n*16 + lr  ->  u = lr*4 + jh*2 + n
__device__ __host__ inline int uperm(int jl) {
  return ((jl & 15) << 2) | (((jl >> 5) & 1) << 1) | ((jl >> 4) & 1);
}

// ---------------- prep: Kn[b][j][c] bf16, Kmt2[b][kt][c][u] bf16 (mask-folded, PV-permuted,
// TILE-PACKED: each (b,kt) tile is 256x64 contiguous), norms[b][j] = ||F_j||*log2e ----------------
__global__ __launch_bounds__(256) void prep_kernel(
    const float* __restrict__ F, const float* __restrict__ mask,
    __bf16* __restrict__ Kn, __bf16* __restrict__ Kmt2, float* __restrict__ norms)
{
  __shared__ float tile[256 * 33];
  __shared__ float red[256];
  __shared__ float invs[32];
  __shared__ float mld[32];
  const int t  = threadIdx.x;
  const int b  = blockIdx.y;
  const int j0 = blockIdx.x * 32;

  {
    const int jj = t & 31, cr = t >> 5;
    for (int it = 0; it < 32; ++it) {
      int c = it * 8 + cr;
      tile[c * 33 + jj] = F[(size_t)(b * CH + c) * HW + j0 + jj];
    }
  }
  if (t < 32) mld[t] = mask[b * HW + j0 + t];
  __syncthreads();

  {
    const int jj = t & 31, part = t >> 5;
    float s = 0.f;
    for (int c = part * 32; c < part * 32 + 32; ++c) {
      float v = tile[c * 33 + jj] + 1e-7f;
      s += v * v;
    }
    red[part * 32 + jj] = s;
  }
  __syncthreads();
  if (t < 32) {
    float s = 0.f;
    for (int p = 0; p < 8; ++p) s += red[p * 32 + t];
    invs[t] = rsqrtf(s);
    norms[b * HW + j0 + t] = sqrtf(s) * LOG2E;
  }
  __syncthreads();

  for (int jj = 0; jj < 32; ++jj) {
    float v  = tile[t * 33 + jj];
    float kn = (v + 1e-7f) * invs[jj];
    Kn[(size_t)(b * HW + j0 + jj) * CH + t] = (__bf16)kn;
    tile[t * 33 + jj] = kn * mld[jj];
  }
  __syncthreads();

  {
    const int jj = t & 31, cr = t >> 5;
    for (int it = 0; it < 32; ++it) {
      int c = it * 8 + cr;
      int j = j0 + jj;
      int t64 = j >> 6, jl = j & 63;
      Kmt2[(((size_t)(b * NKT + t64)) * CH + c) * 64 + uperm(jl)] = (__bf16)tile[c * 33 + jj];
    }
  }
}

// ---------------- skip flags ----------------
__global__ __launch_bounds__(256) void skip_kernel(
    const float* __restrict__ mask, float* __restrict__ flags)
{
  __shared__ float wsum[4];
  const int b = blockIdx.x, t = threadIdx.x;
  float s = 0.f;
  for (int i = t; i < HW; i += 256) s += mask[b * HW + i];
  for (int off = 32; off; off >>= 1) s += __shfl_down(s, off);
  if ((t & 63) == 0) wsum[t >> 6] = s;
  __syncthreads();
  if (t == 0) {
    float tot = wsum[0] + wsum[1] + wsum[2] + wsum[3];
    flags[b] = (tot > (float)(HW - 10)) ? 1.f : 0.f;
  }
}

__device__ inline u32 pkbf(float a, float b) {
  union { __bf16 h[2]; u32 u; } cv;
  cv.h[0] = (__bf16)a; cv.h[1] = (__bf16)b;
  return cv.u;
}

// ---------------- flash attention: no-max softmax, coalesced V via wave-private LDS slab ----------------
// block 256 = 4 waves. wave w: g = w>>1 (q-group of 32), jh = w&1 (j-half of 32) for S^T;
// PV: wave w covers c-slab [64w, 64w+64) x all 64 q, V-tile slab staged in private LDS (dense loads).
// grid 512: combo = bid&7 (one (b,js) per XCD), qt = bid>>3.
__global__ __launch_bounds__(256, 2) void attn_kernel(
    const __bf16* __restrict__ Kn, const __bf16* __restrict__ Kmt2,
    const float* __restrict__ norms,
    __bf16* __restrict__ Opart, float* __restrict__ lhalf, int jn)
{
  __shared__ __align__(16) __bf16 Ks[64 * 256];   // 32KB [j][c], rows 512B, XOR-swz
  __shared__ __align__(16) __bf16 Vs[4 * 64 * 64];// 32KB, 8KB per-wave slab [cl][u], rows 128B, XOR-swz
  __shared__ __align__(16) __bf16 Ps[64 * 72];    // 9KB  [q][u], rows 144B
  char* KsB = (char*)Ks;
  char* PsB = (char*)Ps;

  const int t = threadIdx.x;
  const int w = t >> 6, lane = t & 63, lg = lane >> 4, lr = lane & 15;
  const int g = w >> 1, jh = w & 1;
  char* VsW = (char*)Vs + w * 8192;               // wave-private slab

  const int bid = blockIdx.x;
  const int nc  = 4 * jn;
  int combo, qt;
  if (nc == 8) { combo = bid & 7; qt = bid >> 3; }
  else         { combo = bid % nc; qt = bid / nc; }
  const int b   = combo / jn, js = combo % jn;
  const int KT  = NKT / jn;
  const int kt0 = js * KT;
  const int q0  = qt * QB;

  // staging geometry
  const int r0   = t >> 5;              // Ks rows r0+8i
  const int cbks = (t & 31) * 16;
  const int swzk = (r0 & 7) << 4;

  // Q A-frags: q = q0 + g*32 + m*16 + lr
  bf16x8 qf[2][8];
  #pragma unroll
  for (int m = 0; m < 2; ++m) {
    const __bf16* qrow = Kn + (size_t)(b * HW + q0 + g * 32 + m * 16 + lr) * CH;
    #pragma unroll
    for (int ks = 0; ks < 8; ++ks)
      qf[m][ks] = *(const bf16x8*)(qrow + ks * 32 + lg * 8);
  }
  float nrm[2][4];
  #pragma unroll
  for (int m = 0; m < 2; ++m)
    #pragma unroll
    for (int r = 0; r < 4; ++r)
      nrm[m][r] = norms[b * HW + q0 + g * 32 + m * 16 + lg * 4 + r];

  f32x4 acc[4][4];   // [c = 64w + mt*16 + lg*4 + r][q = nt*16 + lr]
  #pragma unroll
  for (int i = 0; i < 4; ++i)
    #pragma unroll
    for (int j = 0; j < 4; ++j) acc[i][j] = (f32x4)0.f;
  float l_part[2][4];
  #pragma unroll
  for (int m = 0; m < 2; ++m)
    #pragma unroll
    for (int r = 0; r < 4; ++r) l_part[m][r] = 0.f;

  // prologue: stage Ks(kt0) + Vs(kt0)
  {
    uint4 sk[8], sv[8];
    #pragma unroll
    for (int i = 0; i < 8; ++i)
      sk[i] = *(const uint4*)((const char*)(Kn + (size_t)(b * HW + kt0 * KB + r0 + 8 * i) * CH) + cbks);
    const char* vg = (const char*)(Kmt2 + (((size_t)(b * NKT + kt0)) * CH + 64 * w) * 64);
    #pragma unroll
    for (int i = 0; i < 8; ++i)
      sv[i] = *(const uint4*)(vg + i * 1024 + lane * 16);
    #pragma unroll
    for (int i = 0; i < 8; ++i)
      *(uint4*)(KsB + (r0 + 8 * i) * 512 + (cbks ^ swzk)) = sk[i];
    #pragma unroll
    for (int i = 0; i < 8; ++i) {
      int o = i * 1024 + lane * 16;
      *(uint4*)(VsW + (o ^ (((o >> 7) & 7) << 4))) = sv[i];
    }
  }
  __syncthreads();

  for (int k = 0; k < KT; ++k) {
    const int kt = kt0 + k;

    // issue next tile's staging loads (covered by S^T + softmax + PV)
    uint4 sk[8], sv[8];
    if (k + 1 < KT) {
      #pragma unroll
      for (int i = 0; i < 8; ++i)
        sk[i] = *(const uint4*)((const char*)(Kn + (size_t)(b * HW + (kt + 1) * KB + r0 + 8 * i) * CH) + cbks);
      const char* vg = (const char*)(Kmt2 + (((size_t)(b * NKT + kt + 1)) * CH + 64 * w) * 64);
      #pragma unroll
      for (int i = 0; i < 8; ++i)
        sv[i] = *(const uint4*)(vg + i * 1024 + lane * 16);
    }

    // ---- S^T: 2m x 2n x 8ks, A = Q regs, B = Ks LDS (j = jh*32 + n*16 + lr rows) ----
    f32x4 sa[2][2];
    #pragma unroll
    for (int m = 0; m < 2; ++m)
      #pragma unroll
      for (int n = 0; n < 2; ++n) sa[m][n] = (f32x4)0.f;
    __builtin_amdgcn_s_setprio(1);
    #pragma unroll
    for (int ks = 0; ks < 8; ++ks) {
      bf16x8 bb[2];
      #pragma unroll
      for (int n = 0; n < 2; ++n) {
        const int row = jh * 32 + n * 16 + lr;
        bb[n] = *(const bf16x8*)(KsB + row * 512 + ((ks * 64 + lg * 16) ^ ((row & 7) << 4)));
      }
      #pragma unroll
      for (int m = 0; m < 2; ++m)
        #pragma unroll
        for (int n = 0; n < 2; ++n)
          sa[m][n] = __builtin_amdgcn_mfma_f32_16x16x32_bf16(qf[m][ks], bb[n], sa[m][n], 0, 0, 0);
    }
    __builtin_amdgcn_s_setprio(0);

    // ---- no-max softmax: P = exp2(S * nrm'); lane-local l; Ps write ----
    #pragma unroll
    for (int m = 0; m < 2; ++m) {
      #pragma unroll
      for (int r = 0; r < 4; ++r) {
        float e0 = exp2f(sa[m][0][r] * nrm[m][r]);
        float e1 = exp2f(sa[m][1][r] * nrm[m][r]);
        l_part[m][r] += e0 + e1;
        const int q = g * 32 + m * 16 + lg * 4 + r;
        *(u32*)(PsB + q * 144 + 8 * lr + 4 * jh) = pkbf(e0, e1);
      }
    }
    __syncthreads();   // Ks reads done; Ps visible

    // write staged Ks tile k+1 (overlaps PV)
    if (k + 1 < KT) {
      #pragma unroll
      for (int i = 0; i < 8; ++i)
        *(uint4*)(KsB + (r0 + 8 * i) * 512 + (cbks ^ swzk)) = sk[i];
    }

    // ---- PV: acc += V_slab * P; A-frags from wave-private Vs (conflict-free b128) ----
    __builtin_amdgcn_s_setprio(1);
    #pragma unroll
    for (int ks2 = 0; ks2 < 2; ++ks2) {
      bf16x8 pfr[4], va[4];
      #pragma unroll
      for (int nt = 0; nt < 4; ++nt)
        pfr[nt] = *(const bf16x8*)(PsB + (nt * 16 + lr) * 144 + ks2 * 64 + lg * 16);
      #pragma unroll
      for (int mt = 0; mt < 4; ++mt)
        va[mt] = *(const bf16x8*)(VsW + (mt * 16 + lr) * 128 +
                                  ((ks2 * 64 + lg * 16) ^ ((lr & 7) << 4)));
      #pragma unroll
      for (int mt = 0; mt < 4; ++mt)
        #pragma unroll
        for (int nt = 0; nt < 4; ++nt)
          acc[mt][nt] = __builtin_amdgcn_mfma_f32_16x16x32_bf16(va[mt], pfr[nt], acc[mt][nt], 0, 0, 0);
    }
    __builtin_amdgcn_s_setprio(0);

    // write staged Vs tile k+1 (wave-private; after this wave's PV reads — in-order DS stream)
    if (k + 1 < KT) {
      #pragma unroll
      for (int i = 0; i < 8; ++i) {
        int o = i * 1024 + lane * 16;
        *(uint4*)(VsW + (o ^ (((o >> 7) & 7) << 4))) = sv[i];
      }
    }
    __syncthreads();   // Ks[k+1]/Ps-reuse safe
  }

  // ---- epilogue: O~ partial [q][c] (8B packed); l partial per (js, jh) ----
  __bf16* op = Opart + ((size_t)(js * BS + b) * NQT + qt) * QB * CH;
  #pragma unroll
  for (int mt = 0; mt < 4; ++mt) {
    const int cbn = 64 * w + mt * 16 + lg * 4;
    #pragma unroll
    for (int nt = 0; nt < 4; ++nt) {
      const int q = nt * 16 + lr;
      uint2 pw2;
      pw2.x = pkbf(acc[mt][nt][0], acc[mt][nt][1]);
      pw2.y = pkbf(acc[mt][nt][2], acc[mt][nt][3]);
      *(uint2*)(op + (size_t)q * CH + cbn) = pw2;
    }
  }
  #pragma unroll
  for (int m = 0; m < 2; ++m)
    #pragma unroll
    for (int r = 0; r < 4; ++r) {
      float v = l_part[m][r];
      v += __shfl_xor(v, 1); v += __shfl_xor(v, 2);
      v += __shfl_xor(v, 4); v += __shfl_xor(v, 8);
      l_part[m][r] = v;
    }
  if (lr == 0) {
    #pragma unroll
    for (int m = 0; m < 2; ++m)
      #pragma unroll
      for (int r = 0; r < 4; ++r) {
        int qg = q0 + g * 32 + m * 16 + lg * 4 + r;
        lhalf[((size_t)(js * 2 + jh) * BS + b) * HW + qg] = l_part[m][r];
      }
  }
}

// ---------------- combine partials + blend (plain sums) ----------------
__global__ __launch_bounds__(256) void combine_kernel(
    const __bf16* __restrict__ Opart, const float* __restrict__ lhalf,
    const float* __restrict__ F, const float* __restrict__ mask,
    const float* __restrict__ flags, float* __restrict__ out, int jn)
{
  const int bid = blockIdx.x;
  const int cq = bid & 3, chunk = bid >> 2;
  const int t = threadIdx.x;
  const int qg = chunk * 256 + t;
  const int b  = qg >> 12, q = qg & 4095;
  const int qt = q >> 6, ql = q & 63;

  float L = 0.f;
  for (int s = 0; s < 2 * jn; ++s)
    L += lhalf[((size_t)s * BS + b) * HW + q];
  float inv = 1.f / L;
  float msk = mask[b * HW + q];
  float w1 = 1.f - msk;
  bool skip = flags[b] > 0.5f;

  const __bf16* opq[4];
  for (int js = 0; js < jn; ++js)
    opq[js] = Opart + (((size_t)(js * BS + b) * NQT + qt) * QB + ql) * CH;

  for (int c0 = cq * 64; c0 < cq * 64 + 64; c0 += 8) {
    float s8[8];
    #pragma unroll
    for (int e = 0; e < 8; ++e) s8[e] = 0.f;
    for (int js = 0; js < jn; ++js) {
      bf16x8 v = *(const bf16x8*)(opq[js] + c0);
      #pragma unroll
      for (int e = 0; e < 8; ++e) s8[e] += (float)v[e];
    }
    #pragma unroll
    for (int e = 0; e < 8; ++e) {
      size_t idx = ((size_t)b * CH + c0 + e) * HW + q;
      float f = F[idx];
      out[idx] = skip ? f : (s8[e] * inv * w1 + f * msk);
    }
  }
}

extern "C" void kernel_launch(void* const* d_in, const int* in_sizes, int n_in,
                              void* d_out, int out_size, void* d_ws, size_t ws_size,
                              hipStream_t stream) {
  const float* F    = (const float*)d_in[0];
  const float* mask = (const float*)d_in[1];
  float* out = (float*)d_out;

  char* p = (char*)d_ws;
  __bf16* Kn   = (__bf16*)p;  p += (size_t)BS * HW * CH * 2;
  __bf16* Kmt2 = (__bf16*)p;  p += (size_t)BS * HW * CH * 2;   // same size, tile-packed
  float* norms = (float*)p;   p += (size_t)BS * HW * 4;
  float* flags = (float*)p;   p += 256;
  size_t used = (size_t)(p - (char*)d_ws);

  int jn = 2;
  while (jn > 1) {
    size_t need = used + (size_t)jn * ((size_t)2 * BS * HW * 4 + (size_t)BS * NQT * QB * CH * 2);
    if (need <= ws_size) break;
    jn >>= 1;
  }
  float* lh = (float*)p;      p += (size_t)2 * jn * BS * HW * 4;
  __bf16* Opart = (__bf16*)p;

  prep_kernel<<<dim3(HW / 32, BS), 256, 0, stream>>>(F, mask, Kn, Kmt2, norms);
  skip_kernel<<<BS, 256, 0, stream>>>(mask, flags);
  attn_kernel<<<dim3(NQT * 4 * jn), 256, 0, stream>>>(Kn, Kmt2, norms, Opart, lh, jn);
  combine_kernel<<<dim3(256), 256, 0, stream>>>(Opart, lh, F, mask, flags, out, jn);
}

// Round 15
// 180.577 us; speedup vs baseline: 1.7766x; 1.7766x over previous
//
#include <hip/hip_runtime.h>
#include <hip/hip_bf16.h>
#include <math.h>

typedef __bf16 bf16x8 __attribute__((ext_vector_type(8)));
typedef float  f32x4  __attribute__((ext_vector_type(4)));
typedef unsigned int u32;

#define BS 4
#define CH 256
#define HW 4096
#define QB 64           // q-rows per block
#define KB 64           // j per k-tile
#define NKT (HW/KB)     // 64
#define NQT (HW/QB)     // 64
#define LOG2E 1.44269504f

// PV k-slot permutation: j local (0..63) -> u, so a lane's S^T outputs are its PV B slots.
// j = jh*32 + n*16 + lr  ->  u = lr*4 + jh*2 + n
__device__ __host__ inline int uperm(int jl) {
  return ((jl & 15) << 2) | (((jl >> 5) & 1) << 1) | ((jl >> 4) & 1);
}

// ---------------- prep: Kn[b][j][c] bf16, Kmt2[b][kt][c][u] bf16 (mask-folded, PV-permuted,
// tile-packed 256x64 per (b,kt)), norms[b][j] = ||F_j||*log2e ----------------
__global__ __launch_bounds__(256) void prep_kernel(
    const float* __restrict__ F, const float* __restrict__ mask,
    __bf16* __restrict__ Kn, __bf16* __restrict__ Kmt2, float* __restrict__ norms)
{
  __shared__ float tile[256 * 33];
  __shared__ float red[256];
  __shared__ float invs[32];
  __shared__ float mld[32];
  const int t  = threadIdx.x;
  const int b  = blockIdx.y;
  const int j0 = blockIdx.x * 32;

  {
    const int jj = t & 31, cr = t >> 5;
    for (int it = 0; it < 32; ++it) {
      int c = it * 8 + cr;
      tile[c * 33 + jj] = F[(size_t)(b * CH + c) * HW + j0 + jj];
    }
  }
  if (t < 32) mld[t] = mask[b * HW + j0 + t];
  __syncthreads();

  {
    const int jj = t & 31, part = t >> 5;
    float s = 0.f;
    for (int c = part * 32; c < part * 32 + 32; ++c) {
      float v = tile[c * 33 + jj] + 1e-7f;
      s += v * v;
    }
    red[part * 32 + jj] = s;
  }
  __syncthreads();
  if (t < 32) {
    float s = 0.f;
    for (int p = 0; p < 8; ++p) s += red[p * 32 + t];
    invs[t] = rsqrtf(s);
    norms[b * HW + j0 + t] = sqrtf(s) * LOG2E;
  }
  __syncthreads();

  for (int jj = 0; jj < 32; ++jj) {
    float v  = tile[t * 33 + jj];
    float kn = (v + 1e-7f) * invs[jj];
    Kn[(size_t)(b * HW + j0 + jj) * CH + t] = (__bf16)kn;
    tile[t * 33 + jj] = kn * mld[jj];
  }
  __syncthreads();

  {
    const int jj = t & 31, cr = t >> 5;
    for (int it = 0; it < 32; ++it) {
      int c = it * 8 + cr;
      int j = j0 + jj;
      int t64 = j >> 6, jl = j & 63;
      Kmt2[(((size_t)(b * NKT + t64)) * CH + c) * 64 + uperm(jl)] = (__bf16)tile[c * 33 + jj];
    }
  }
}

// ---------------- skip flags ----------------
__global__ __launch_bounds__(256) void skip_kernel(
    const float* __restrict__ mask, float* __restrict__ flags)
{
  __shared__ float wsum[4];
  const int b = blockIdx.x, t = threadIdx.x;
  float s = 0.f;
  for (int i = t; i < HW; i += 256) s += mask[b * HW + i];
  for (int off = 32; off; off >>= 1) s += __shfl_down(s, off);
  if ((t & 63) == 0) wsum[t >> 6] = s;
  __syncthreads();
  if (t == 0) {
    float tot = wsum[0] + wsum[1] + wsum[2] + wsum[3];
    flags[b] = (tot > (float)(HW - 10)) ? 1.f : 0.f;
  }
}

__device__ inline u32 pkbf(float a, float b) {
  union { __bf16 h[2]; u32 u; } cv;
  cv.h[0] = (__bf16)a; cv.h[1] = (__bf16)b;
  return cv.u;
}

// ---------------- flash attention: 8-wave blocks, spill-free registers, GLL Ks staging ----------------
// block 512 = 8 waves. wave w: g = w>>1 (q-group of 16), jh = w&1 (j-half of 32) for S^T;
// PV: wave w covers c-slab [32w, 32w+32) x all 64 q.
// grid 512 = 2 blocks/CU exactly; combo = bid&7 (one (b,js) per XCD), qt = bid>>3.
__global__ __launch_bounds__(512, 2) void attn_kernel(
    const __bf16* __restrict__ Kn, const __bf16* __restrict__ Kmt2,
    const float* __restrict__ norms,
    __bf16* __restrict__ Opart, float* __restrict__ lhalf, int jn)
{
  __shared__ __align__(16) __bf16 Ks[64 * 256];   // 32KB [j][c], rows 512B, XOR-swz
  __shared__ __align__(16) __bf16 Ps[64 * 72];    // 9KB  [q][u], rows 144B
  char* KsB = (char*)Ks;
  char* PsB = (char*)Ps;

  const int t = threadIdx.x;
  const int w = t >> 6, lane = t & 63, lg = lane >> 4, lr = lane & 15;
  const int g = w >> 1, jh = w & 1;
  const int l5 = lane >> 5;

  const int bid = blockIdx.x;
  const int nc  = 4 * jn;
  int combo, qt;
  if (nc == 8) { combo = bid & 7; qt = bid >> 3; }
  else         { combo = bid % nc; qt = bid / nc; }
  const int b   = combo / jn, js = combo % jn;
  const int KT  = NKT / jn;
  const int kt0 = js * KT;
  const int q0  = qt * QB;

  // GLL staging geometry: thread covers rows rr = i*16 + w*2 + l5, i<4; 16B at cb
  const int cb = (lane & 31) * 16;

  // Q A-frags: q = q0 + g*16 + lr  (32 VGPR)
  bf16x8 qf[8];
  {
    const __bf16* qrow = Kn + (size_t)(b * HW + q0 + g * 16 + lr) * CH;
    #pragma unroll
    for (int ks = 0; ks < 8; ++ks)
      qf[ks] = *(const bf16x8*)(qrow + ks * 32 + lg * 8);
  }
  float nrm[4];
  #pragma unroll
  for (int r = 0; r < 4; ++r)
    nrm[r] = norms[b * HW + q0 + g * 16 + lg * 4 + r];

  f32x4 acc[2][4];   // [c = 32w + mt*16 + lg*4 + r][q = nt*16 + lr]  (32 VGPR)
  #pragma unroll
  for (int i = 0; i < 2; ++i)
    #pragma unroll
    for (int j = 0; j < 4; ++j) acc[i][j] = (f32x4)0.f;
  float l_part[4];
  #pragma unroll
  for (int r = 0; r < 4; ++r) l_part[r] = 0.f;

  // prologue: GLL-stage Ks(kt0) — linear LDS dest, source-swizzled
  #pragma unroll
  for (int i = 0; i < 4; ++i) {
    const int rr = i * 16 + w * 2 + l5;
    const char* gsrc = (const char*)(Kn + (size_t)(b * HW + kt0 * KB + rr) * CH) +
                       (cb ^ ((rr & 7) << 4));
    char* ldst = KsB + (i * 16 + w * 2) * 512;   // wave-uniform base (+lane*16 by HW)
    __builtin_amdgcn_global_load_lds(
        (const __attribute__((address_space(1))) u32*)gsrc,
        (__attribute__((address_space(3))) u32*)ldst, 16, 0, 0);
  }
  __syncthreads();

  for (int k = 0; k < KT; ++k) {
    const int kt = kt0 + k;

    // ---- S^T: 1m x 2n x 8ks, A = Q regs, B = Ks LDS (j = jh*32 + n*16 + lr rows) ----
    f32x4 sa[2];
    #pragma unroll
    for (int n = 0; n < 2; ++n) sa[n] = (f32x4)0.f;
    __builtin_amdgcn_s_setprio(1);
    #pragma unroll
    for (int ks = 0; ks < 8; ++ks) {
      bf16x8 bb[2];
      #pragma unroll
      for (int n = 0; n < 2; ++n) {
        const int row = jh * 32 + n * 16 + lr;
        bb[n] = *(const bf16x8*)(KsB + row * 512 + ((ks * 64 + lg * 16) ^ ((row & 7) << 4)));
      }
      #pragma unroll
      for (int n = 0; n < 2; ++n)
        sa[n] = __builtin_amdgcn_mfma_f32_16x16x32_bf16(qf[ks], bb[n], sa[n], 0, 0, 0);
    }
    __builtin_amdgcn_s_setprio(0);

    // ---- no-max softmax: P = exp2(S * nrm'); lane-local l; Ps write ----
    #pragma unroll
    for (int r = 0; r < 4; ++r) {
      float e0 = exp2f(sa[0][r] * nrm[r]);
      float e1 = exp2f(sa[1][r] * nrm[r]);
      l_part[r] += e0 + e1;
      const int q = g * 16 + lg * 4 + r;
      *(u32*)(PsB + q * 144 + 8 * lr + 4 * jh) = pkbf(e0, e1);
    }
    __syncthreads();   // Ks reads done; Ps visible

    // GLL-stage Ks(k+1) — lands before barrier2's vmcnt drain, overlaps PV
    if (k + 1 < KT) {
      #pragma unroll
      for (int i = 0; i < 4; ++i) {
        const int rr = i * 16 + w * 2 + l5;
        const char* gsrc = (const char*)(Kn + (size_t)(b * HW + (kt + 1) * KB + rr) * CH) +
                           (cb ^ ((rr & 7) << 4));
        char* ldst = KsB + (i * 16 + w * 2) * 512;
        __builtin_amdgcn_global_load_lds(
            (const __attribute__((address_space(1))) u32*)gsrc,
            (__attribute__((address_space(3))) u32*)ldst, 16, 0, 0);
      }
    }

    // ---- PV: acc += V_tile * P; km transient from tile-packed Kmt2 ----
    __builtin_amdgcn_s_setprio(1);
    #pragma unroll
    for (int ks2 = 0; ks2 < 2; ++ks2) {
      bf16x8 pfr[4], km[2];
      #pragma unroll
      for (int nt = 0; nt < 4; ++nt)
        pfr[nt] = *(const bf16x8*)(PsB + (nt * 16 + lr) * 144 + ks2 * 64 + lg * 16);
      #pragma unroll
      for (int mt = 0; mt < 2; ++mt)
        km[mt] = *(const bf16x8*)(Kmt2 + (((size_t)(b * NKT + kt)) * CH + 32 * w + mt * 16 + lr) * 64 +
                                  ks2 * 32 + lg * 8);
      #pragma unroll
      for (int mt = 0; mt < 2; ++mt)
        #pragma unroll
        for (int nt = 0; nt < 4; ++nt)
          acc[mt][nt] = __builtin_amdgcn_mfma_f32_16x16x32_bf16(km[mt], pfr[nt], acc[mt][nt], 0, 0, 0);
    }
    __builtin_amdgcn_s_setprio(0);
    __syncthreads();   // Ks[k+1] visible (vmcnt drained); Ps reads done
  }

  // ---- epilogue: O~ partial [q][c] (8B packed); l partial per (js, jh) ----
  __bf16* op = Opart + ((size_t)(js * BS + b) * NQT + qt) * QB * CH;
  #pragma unroll
  for (int mt = 0; mt < 2; ++mt) {
    const int cbn = 32 * w + mt * 16 + lg * 4;
    #pragma unroll
    for (int nt = 0; nt < 4; ++nt) {
      const int q = nt * 16 + lr;
      uint2 pw2;
      pw2.x = pkbf(acc[mt][nt][0], acc[mt][nt][1]);
      pw2.y = pkbf(acc[mt][nt][2], acc[mt][nt][3]);
      *(uint2*)(op + (size_t)q * CH + cbn) = pw2;
    }
  }
  #pragma unroll
  for (int r = 0; r < 4; ++r) {
    float v = l_part[r];
    v += __shfl_xor(v, 1); v += __shfl_xor(v, 2);
    v += __shfl_xor(v, 4); v += __shfl_xor(v, 8);
    l_part[r] = v;
  }
  if (lr == 0) {
    #pragma unroll
    for (int r = 0; r < 4; ++r) {
      int qg = q0 + g * 16 + lg * 4 + r;
      lhalf[((size_t)(js * 2 + jh) * BS + b) * HW + qg] = l_part[r];
    }
  }
}

// ---------------- combine partials + blend (plain sums) ----------------
__global__ __launch_bounds__(256) void combine_kernel(
    const __bf16* __restrict__ Opart, const float* __restrict__ lhalf,
    const float* __restrict__ F, const float* __restrict__ mask,
    const float* __restrict__ flags, float* __restrict__ out, int jn)
{
  const int bid = blockIdx.x;
  const int cq = bid & 3, chunk = bid >> 2;
  const int t = threadIdx.x;
  const int qg = chunk * 256 + t;
  const int b  = qg >> 12, q = qg & 4095;
  const int qt = q >> 6, ql = q & 63;

  float L = 0.f;
  for (int s = 0; s < 2 * jn; ++s)
    L += lhalf[((size_t)s * BS + b) * HW + q];
  float inv = 1.f / L;
  float msk = mask[b * HW + q];
  float w1 = 1.f - msk;
  bool skip = flags[b] > 0.5f;

  const __bf16* opq[4];
  for (int js = 0; js < jn; ++js)
    opq[js] = Opart + (((size_t)(js * BS + b) * NQT + qt) * QB + ql) * CH;

  for (int c0 = cq * 64; c0 < cq * 64 + 64; c0 += 8) {
    float s8[8];
    #pragma unroll
    for (int e = 0; e < 8; ++e) s8[e] = 0.f;
    for (int js = 0; js < jn; ++js) {
      bf16x8 v = *(const bf16x8*)(opq[js] + c0);
      #pragma unroll
      for (int e = 0; e < 8; ++e) s8[e] += (float)v[e];
    }
    #pragma unroll
    for (int e = 0; e < 8; ++e) {
      size_t idx = ((size_t)b * CH + c0 + e) * HW + q;
      float f = F[idx];
      out[idx] = skip ? f : (s8[e] * inv * w1 + f * msk);
    }
  }
}

extern "C" void kernel_launch(void* const* d_in, const int* in_sizes, int n_in,
                              void* d_out, int out_size, void* d_ws, size_t ws_size,
                              hipStream_t stream) {
  const float* F    = (const float*)d_in[0];
  const float* mask = (const float*)d_in[1];
  float* out = (float*)d_out;

  char* p = (char*)d_ws;
  __bf16* Kn   = (__bf16*)p;  p += (size_t)BS * HW * CH * 2;
  __bf16* Kmt2 = (__bf16*)p;  p += (size_t)BS * HW * CH * 2;   // tile-packed
  float* norms = (float*)p;   p += (size_t)BS * HW * 4;
  float* flags = (float*)p;   p += 256;
  size_t used = (size_t)(p - (char*)d_ws);

  int jn = 2;
  while (jn > 1) {
    size_t need = used + (size_t)jn * ((size_t)2 * BS * HW * 4 + (size_t)BS * NQT * QB * CH * 2);
    if (need <= ws_size) break;
    jn >>= 1;
  }
  float* lh = (float*)p;      p += (size_t)2 * jn * BS * HW * 4;
  __bf16* Opart = (__bf16*)p;

  prep_kernel<<<dim3(HW / 32, BS), 256, 0, stream>>>(F, mask, Kn, Kmt2, norms);
  skip_kernel<<<BS, 256, 0, stream>>>(mask, flags);
  attn_kernel<<<dim3(NQT * 4 * jn), 512, 0, stream>>>(Kn, Kmt2, norms, Opart, lh, jn);
  combine_kernel<<<dim3(256), 256, 0, stream>>>(Opart, lh, F, mask, flags, out, jn);
}

// Round 16
// 147.543 us; speedup vs baseline: 2.1744x; 1.2239x over previous
//
#include <hip/hip_runtime.h>
#include <hip/hip_bf16.h>
#include <math.h>

typedef __bf16 bf16x8 __attribute__((ext_vector_type(8)));
typedef float  f32x4  __attribute__((ext_vector_type(4)));
typedef unsigned int u32;

#define BS 4
#define CH 256
#define HW 4096
#define QB 64           // q-rows per block
#define KB 64           // j per k-tile
#define NKT (HW/KB)     // 64
#define NQT (HW/QB)     // 64
#define LOG2E 1.44269504f

// PV k-slot permutation: j local (0..63) -> u, so a lane's S^T outputs are its PV B slots.
// j = jh*32 + n*16 + lr  ->  u = lr*4 + jh*2 + n
__device__ __host__ inline int uperm(int jl) {
  return ((jl & 15) << 2) | (((jl >> 5) & 1) << 1) | ((jl >> 4) & 1);
}

// ---------------- prep: Kn[b][j][c] bf16, Kmt2[b][kt][c][u] bf16 (mask-folded, PV-permuted,
// tile-packed 256x64 per (b,kt)), norms[b][j] = ||F_j||*log2e ----------------
__global__ __launch_bounds__(256) void prep_kernel(
    const float* __restrict__ F, const float* __restrict__ mask,
    __bf16* __restrict__ Kn, __bf16* __restrict__ Kmt2, float* __restrict__ norms)
{
  __shared__ float tile[256 * 33];
  __shared__ float red[256];
  __shared__ float invs[32];
  __shared__ float mld[32];
  const int t  = threadIdx.x;
  const int b  = blockIdx.y;
  const int j0 = blockIdx.x * 32;

  {
    const int jj = t & 31, cr = t >> 5;
    for (int it = 0; it < 32; ++it) {
      int c = it * 8 + cr;
      tile[c * 33 + jj] = F[(size_t)(b * CH + c) * HW + j0 + jj];
    }
  }
  if (t < 32) mld[t] = mask[b * HW + j0 + t];
  __syncthreads();

  {
    const int jj = t & 31, part = t >> 5;
    float s = 0.f;
    for (int c = part * 32; c < part * 32 + 32; ++c) {
      float v = tile[c * 33 + jj] + 1e-7f;
      s += v * v;
    }
    red[part * 32 + jj] = s;
  }
  __syncthreads();
  if (t < 32) {
    float s = 0.f;
    for (int p = 0; p < 8; ++p) s += red[p * 32 + t];
    invs[t] = rsqrtf(s);
    norms[b * HW + j0 + t] = sqrtf(s) * LOG2E;
  }
  __syncthreads();

  for (int jj = 0; jj < 32; ++jj) {
    float v  = tile[t * 33 + jj];
    float kn = (v + 1e-7f) * invs[jj];
    Kn[(size_t)(b * HW + j0 + jj) * CH + t] = (__bf16)kn;
    tile[t * 33 + jj] = kn * mld[jj];
  }
  __syncthreads();

  {
    const int jj = t & 31, cr = t >> 5;
    for (int it = 0; it < 32; ++it) {
      int c = it * 8 + cr;
      int j = j0 + jj;
      int t64 = j >> 6, jl = j & 63;
      Kmt2[(((size_t)(b * NKT + t64)) * CH + c) * 64 + uperm(jl)] = (__bf16)tile[c * 33 + jj];
    }
  }
}

// ---------------- skip flags ----------------
__global__ __launch_bounds__(256) void skip_kernel(
    const float* __restrict__ mask, float* __restrict__ flags)
{
  __shared__ float wsum[4];
  const int b = blockIdx.x, t = threadIdx.x;
  float s = 0.f;
  for (int i = t; i < HW; i += 256) s += mask[b * HW + i];
  for (int off = 32; off; off >>= 1) s += __shfl_down(s, off);
  if ((t & 63) == 0) wsum[t >> 6] = s;
  __syncthreads();
  if (t == 0) {
    float tot = wsum[0] + wsum[1] + wsum[2] + wsum[3];
    flags[b] = (tot > (float)(HW - 10)) ? 1.f : 0.f;
  }
}

__device__ inline u32 pkbf(float a, float b) {
  union { __bf16 h[2]; u32 u; } cv;
  cv.h[0] = (__bf16)a; cv.h[1] = (__bf16)b;
  return cv.u;
}

// ---------------- flash attention: 8-wave blocks, 2 blocks/CU, km prefetch ----------------
// block 512 = 8 waves. wave w: g = w>>1 (q-group of 16), jh = w&1 (j-half of 32) for S^T;
// PV: wave w covers c-slab [32w, 32w+32) x all 64 q.
// grid 512 = 2 blocks/CU (launch_bounds 512,4 -> k=2); combo = bid&7, qt = bid>>3.
__global__ __launch_bounds__(512, 4) void attn_kernel(
    const __bf16* __restrict__ Kn, const __bf16* __restrict__ Kmt2,
    const float* __restrict__ norms,
    __bf16* __restrict__ Opart, float* __restrict__ lhalf, int jn)
{
  __shared__ __align__(16) __bf16 Ks[64 * 256];   // 32KB [j][c], rows 512B, XOR-swz
  __shared__ __align__(16) __bf16 Ps[64 * 72];    // 9KB  [q][u], rows 144B
  char* KsB = (char*)Ks;
  char* PsB = (char*)Ps;

  const int t = threadIdx.x;
  const int w = t >> 6, lane = t & 63, lg = lane >> 4, lr = lane & 15;
  const int g = w >> 1, jh = w & 1;
  const int l5 = lane >> 5;

  const int bid = blockIdx.x;
  const int nc  = 4 * jn;
  int combo, qt;
  if (nc == 8) { combo = bid & 7; qt = bid >> 3; }
  else         { combo = bid % nc; qt = bid / nc; }
  const int b   = combo / jn, js = combo % jn;
  const int KT  = NKT / jn;
  const int kt0 = js * KT;
  const int q0  = qt * QB;

  // GLL staging geometry: thread covers rows rr = i*16 + w*2 + l5, i<4; 16B at cb
  const int cb = (lane & 31) * 16;

  // Q A-frags: q = q0 + g*16 + lr  (32 VGPR)
  bf16x8 qf[8];
  {
    const __bf16* qrow = Kn + (size_t)(b * HW + q0 + g * 16 + lr) * CH;
    #pragma unroll
    for (int ks = 0; ks < 8; ++ks)
      qf[ks] = *(const bf16x8*)(qrow + ks * 32 + lg * 8);
  }
  float nrm[4];
  #pragma unroll
  for (int r = 0; r < 4; ++r)
    nrm[r] = norms[b * HW + q0 + g * 16 + lg * 4 + r];

  f32x4 acc[2][4];   // [c = 32w + mt*16 + lg*4 + r][q = nt*16 + lr]  (32 VGPR)
  #pragma unroll
  for (int i = 0; i < 2; ++i)
    #pragma unroll
    for (int j = 0; j < 4; ++j) acc[i][j] = (f32x4)0.f;
  float l_part[4];
  #pragma unroll
  for (int r = 0; r < 4; ++r) l_part[r] = 0.f;

  // prologue: GLL-stage Ks(kt0) — linear LDS dest, source-swizzled
  #pragma unroll
  for (int i = 0; i < 4; ++i) {
    const int rr = i * 16 + w * 2 + l5;
    const char* gsrc = (const char*)(Kn + (size_t)(b * HW + kt0 * KB + rr) * CH) +
                       (cb ^ ((rr & 7) << 4));
    char* ldst = KsB + (i * 16 + w * 2) * 512;   // wave-uniform base (+lane*16 by HW)
    __builtin_amdgcn_global_load_lds(
        (const __attribute__((address_space(1))) u32*)gsrc,
        (__attribute__((address_space(3))) u32*)ldst, 16, 0, 0);
  }
  __syncthreads();

  for (int k = 0; k < KT; ++k) {
    const int kt = kt0 + k;

    // prefetch this tile's km (V) fragments — L2 latency hides under S^T + softmax
    bf16x8 km[2][2];
    #pragma unroll
    for (int ks2 = 0; ks2 < 2; ++ks2)
      #pragma unroll
      for (int mt = 0; mt < 2; ++mt)
        km[ks2][mt] = *(const bf16x8*)(Kmt2 + (((size_t)(b * NKT + kt)) * CH + 32 * w + mt * 16 + lr) * 64 +
                                       ks2 * 32 + lg * 8);

    // ---- S^T: 1m x 2n x 8ks, A = Q regs, B = Ks LDS (j = jh*32 + n*16 + lr rows) ----
    f32x4 sa[2];
    #pragma unroll
    for (int n = 0; n < 2; ++n) sa[n] = (f32x4)0.f;
    __builtin_amdgcn_s_setprio(1);
    #pragma unroll
    for (int ks = 0; ks < 8; ++ks) {
      bf16x8 bb[2];
      #pragma unroll
      for (int n = 0; n < 2; ++n) {
        const int row = jh * 32 + n * 16 + lr;
        bb[n] = *(const bf16x8*)(KsB + row * 512 + ((ks * 64 + lg * 16) ^ ((row & 7) << 4)));
      }
      #pragma unroll
      for (int n = 0; n < 2; ++n)
        sa[n] = __builtin_amdgcn_mfma_f32_16x16x32_bf16(qf[ks], bb[n], sa[n], 0, 0, 0);
    }
    __builtin_amdgcn_s_setprio(0);

    // ---- no-max softmax: P = exp2(S * nrm'); lane-local l; Ps write ----
    #pragma unroll
    for (int r = 0; r < 4; ++r) {
      float e0 = exp2f(sa[0][r] * nrm[r]);
      float e1 = exp2f(sa[1][r] * nrm[r]);
      l_part[r] += e0 + e1;
      const int q = g * 16 + lg * 4 + r;
      *(u32*)(PsB + q * 144 + 8 * lr + 4 * jh) = pkbf(e0, e1);
    }
    __syncthreads();   // Ks reads done; Ps visible

    // GLL-stage Ks(k+1) — lands before barrier2's vmcnt drain, overlaps PV
    if (k + 1 < KT) {
      #pragma unroll
      for (int i = 0; i < 4; ++i) {
        const int rr = i * 16 + w * 2 + l5;
        const char* gsrc = (const char*)(Kn + (size_t)(b * HW + (kt + 1) * KB + rr) * CH) +
                           (cb ^ ((rr & 7) << 4));
        char* ldst = KsB + (i * 16 + w * 2) * 512;
        __builtin_amdgcn_global_load_lds(
            (const __attribute__((address_space(1))) u32*)gsrc,
            (__attribute__((address_space(3))) u32*)ldst, 16, 0, 0);
      }
    }

    // ---- PV: acc += V_tile * P; km already in regs ----
    __builtin_amdgcn_s_setprio(1);
    #pragma unroll
    for (int ks2 = 0; ks2 < 2; ++ks2) {
      bf16x8 pfr[4];
      #pragma unroll
      for (int nt = 0; nt < 4; ++nt)
        pfr[nt] = *(const bf16x8*)(PsB + (nt * 16 + lr) * 144 + ks2 * 64 + lg * 16);
      #pragma unroll
      for (int mt = 0; mt < 2; ++mt)
        #pragma unroll
        for (int nt = 0; nt < 4; ++nt)
          acc[mt][nt] = __builtin_amdgcn_mfma_f32_16x16x32_bf16(km[ks2][mt], pfr[nt], acc[mt][nt], 0, 0, 0);
    }
    __builtin_amdgcn_s_setprio(0);
    __syncthreads();   // Ks[k+1] visible (vmcnt drained); Ps reads done
  }

  // ---- epilogue: O~ partial [q][c] (8B packed); l partial per (js, jh) ----
  __bf16* op = Opart + ((size_t)(js * BS + b) * NQT + qt) * QB * CH;
  #pragma unroll
  for (int mt = 0; mt < 2; ++mt) {
    const int cbn = 32 * w + mt * 16 + lg * 4;
    #pragma unroll
    for (int nt = 0; nt < 4; ++nt) {
      const int q = nt * 16 + lr;
      uint2 pw2;
      pw2.x = pkbf(acc[mt][nt][0], acc[mt][nt][1]);
      pw2.y = pkbf(acc[mt][nt][2], acc[mt][nt][3]);
      *(uint2*)(op + (size_t)q * CH + cbn) = pw2;
    }
  }
  #pragma unroll
  for (int r = 0; r < 4; ++r) {
    float v = l_part[r];
    v += __shfl_xor(v, 1); v += __shfl_xor(v, 2);
    v += __shfl_xor(v, 4); v += __shfl_xor(v, 8);
    l_part[r] = v;
  }
  if (lr == 0) {
    #pragma unroll
    for (int r = 0; r < 4; ++r) {
      int qg = q0 + g * 16 + lg * 4 + r;
      lhalf[((size_t)(js * 2 + jh) * BS + b) * HW + qg] = l_part[r];
    }
  }
}

// ---------------- combine partials + blend (plain sums) ----------------
__global__ __launch_bounds__(256) void combine_kernel(
    const __bf16* __restrict__ Opart, const float* __restrict__ lhalf,
    const float* __restrict__ F, const float* __restrict__ mask,
    const float* __restrict__ flags, float* __restrict__ out, int jn)
{
  const int bid = blockIdx.x;
  const int cq = bid & 3, chunk = bid >> 2;
  const int t = threadIdx.x;
  const int qg = chunk * 256 + t;
  const int b  = qg >> 12, q = qg & 4095;
  const int qt = q >> 6, ql = q & 63;

  float L = 0.f;
  for (int s = 0; s < 2 * jn; ++s)
    L += lhalf[((size_t)s * BS + b) * HW + q];
  float inv = 1.f / L;
  float msk = mask[b * HW + q];
  float w1 = 1.f - msk;
  bool skip = flags[b] > 0.5f;

  const __bf16* opq[4];
  for (int js = 0; js < jn; ++js)
    opq[js] = Opart + (((size_t)(js * BS + b) * NQT + qt) * QB + ql) * CH;

  for (int c0 = cq * 64; c0 < cq * 64 + 64; c0 += 8) {
    float s8[8];
    #pragma unroll
    for (int e = 0; e < 8; ++e) s8[e] = 0.f;
    for (int js = 0; js < jn; ++js) {
      bf16x8 v = *(const bf16x8*)(opq[js] + c0);
      #pragma unroll
      for (int e = 0; e < 8; ++e) s8[e] += (float)v[e];
    }
    #pragma unroll
    for (int e = 0; e < 8; ++e) {
      size_t idx = ((size_t)b * CH + c0 + e) * HW + q;
      float f = F[idx];
      out[idx] = skip ? f : (s8[e] * inv * w1 + f * msk);
    }
  }
}

extern "C" void kernel_launch(void* const* d_in, const int* in_sizes, int n_in,
                              void* d_out, int out_size, void* d_ws, size_t ws_size,
                              hipStream_t stream) {
  const float* F    = (const float*)d_in[0];
  const float* mask = (const float*)d_in[1];
  float* out = (float*)d_out;

  char* p = (char*)d_ws;
  __bf16* Kn   = (__bf16*)p;  p += (size_t)BS * HW * CH * 2;
  __bf16* Kmt2 = (__bf16*)p;  p += (size_t)BS * HW * CH * 2;   // tile-packed
  float* norms = (float*)p;   p += (size_t)BS * HW * 4;
  float* flags = (float*)p;   p += 256;
  size_t used = (size_t)(p - (char*)d_ws);

  int jn = 2;
  while (jn > 1) {
    size_t need = used + (size_t)jn * ((size_t)2 * BS * HW * 4 + (size_t)BS * NQT * QB * CH * 2);
    if (need <= ws_size) break;
    jn >>= 1;
  }
  float* lh = (float*)p;      p += (size_t)2 * jn * BS * HW * 4;
  __bf16* Opart = (__bf16*)p;

  prep_kernel<<<dim3(HW / 32, BS), 256, 0, stream>>>(F, mask, Kn, Kmt2, norms);
  skip_kernel<<<BS, 256, 0, stream>>>(mask, flags);
  attn_kernel<<<dim3(NQT * 4 * jn), 512, 0, stream>>>(Kn, Kmt2, norms, Opart, lh, jn);
  combine_kernel<<<dim3(256), 256, 0, stream>>>(Opart, lh, F, mask, flags, out, jn);
}